// Round 11
// baseline (157.868 us; speedup 1.0000x reference)
//
#include <hip/hip_runtime.h>

#define KLEN 2048
#define SCH 8           // trellis steps per thread
#define TPR 256         // threads per row (4 waves)
#define NEGV (-1e4f)

struct SM {
  float y1[KLEN];             // systematic, natural order
  float y1i[KLEN];            // systematic, interleaved
  float Lint[KLEN];           // La for decoder 1 (natural)
  float A[KLEN];              // La for decoder 2 (interleaved); bits staging
  unsigned short perm[KLEN];
  unsigned short invp[KLEN];
  float fT[4][16];            // per-wave totals (fwd total == bwd total)
  unsigned int eT[4][2];      // encoder wave totals
};

__device__ __forceinline__ float max4(float a, float b, float c, float d) {
  return fmaxf(fmaxf(fmaxf(a, b), c), d);   // v_max3 + v_max
}

// DPP shift; lanes that are invalid (out-of-row shift source) or write-masked
// (ROW_MASK) retain `old` = max-plus identity element, making the subsequent
// combine a no-op there. Canonical AMD wave64 scan masking: bcast15 ->
// row_mask 0xA, bcast31 -> row_mask 0xC (unlisted rows of bcast modes are NOT
// invalid-source lanes; they must be write-masked).
template <int CTRL, int ROW_MASK>
__device__ __forceinline__ float dpp_id(float src, float idelem) {
  return __int_as_float(__builtin_amdgcn_update_dpp(
      __float_as_int(idelem), __float_as_int(src), CTRL, ROW_MASK, 0xF, false));
}

template <int CTRL, int ROW_MASK>
__device__ __forceinline__ void shift16_id(const float (&X)[16], float (&T)[16]) {
#pragma unroll
  for (int e = 0; e < 16; ++e) {
    const float id = (e == 0 || e == 5 || e == 10 || e == 15) ? 0.f : NEGV;
    T[e] = dpp_id<CTRL, ROW_MASK>(X[e], id);
  }
}

__device__ __forceinline__ void cp16(float (&D)[16], const float (&S)[16]) {
#pragma unroll
  for (int e = 0; e < 16; ++e) D[e] = S[e];
}

// Z = X (later) (x) Y (earlier), max-plus, row-major M[i*4+k]
__device__ __forceinline__ void comb(const float (&X)[16], const float (&Y)[16],
                                     float (&Z)[16]) {
#pragma unroll
  for (int i = 0; i < 4; ++i)
#pragma unroll
    for (int j = 0; j < 4; ++j)
      Z[i * 4 + j] = max4(X[i * 4 + 0] + Y[0 * 4 + j], X[i * 4 + 1] + Y[1 * 4 + j],
                          X[i * 4 + 2] + Y[2 * 4 + j], X[i * 4 + 3] + Y[3 * 4 + j]);
}

// f' = T (x) f  (column-vector pushed forward through later matrix T)
__device__ __forceinline__ void matcol(const float* T, float (&f)[4]) {
  float r0 = max4(T[0]  + f[0], T[1]  + f[1], T[2]  + f[2], T[3]  + f[3]);
  float r1 = max4(T[4]  + f[0], T[5]  + f[1], T[6]  + f[2], T[7]  + f[3]);
  float r2 = max4(T[8]  + f[0], T[9]  + f[1], T[10] + f[2], T[11] + f[3]);
  float r3 = max4(T[12] + f[0], T[13] + f[1], T[14] + f[2], T[15] + f[3]);
  f[0] = r0; f[1] = r1; f[2] = r2; f[3] = r3;
}

// u' = u (x) T  (row-vector pulled backward through earlier matrix T)
__device__ __forceinline__ void rowmat(float (&u)[4], const float* T) {
  float c0 = max4(u[0] + T[0], u[1] + T[4], u[2] + T[8],  u[3] + T[12]);
  float c1 = max4(u[0] + T[1], u[1] + T[5], u[2] + T[9],  u[3] + T[13]);
  float c2 = max4(u[0] + T[2], u[1] + T[6], u[2] + T[10], u[3] + T[14]);
  float c3 = max4(u[0] + T[3], u[1] + T[7], u[2] + T[11], u[3] + T[15]);
  u[0] = c0; u[1] = c1; u[2] = c2; u[3] = c3;
}

// chunk matrix over SCH steps from butterfly terms x=p+q, y=p-q.
// Steps 0+1 fused (pure adds). NO normalization.
__device__ __forceinline__ void buildM(const float (&x)[SCH], const float (&y)[SCH],
                                       float (&M)[16]) {
  const float x0 = x[0], y0 = y[0], x1 = x[1], y1 = y[1];
  M[0]  = -x0 - x1;  M[4]  =  x0 + y1;  M[8]  = -x0 + x1;  M[12] =  x0 - y1;  // col0
  M[1]  =  x0 - x1;  M[5]  = -x0 + y1;  M[9]  =  x0 + x1;  M[13] = -x0 - y1;  // col1
  M[2]  =  y0 + x1;  M[6]  = -y0 - y1;  M[10] =  y0 - x1;  M[14] = -y0 + y1;  // col2
  M[3]  = -y0 + x1;  M[7]  =  y0 - y1;  M[11] = -y0 - x1;  M[15] =  y0 + y1;  // col3
#pragma unroll
  for (int k = 2; k < SCH; ++k) {
    float ppq = x[k], pmq = y[k];
#pragma unroll
    for (int j = 0; j < 4; ++j) {
      float r0 = M[0 * 4 + j], r1 = M[1 * 4 + j], r2 = M[2 * 4 + j], r3 = M[3 * 4 + j];
      M[0 * 4 + j] = fmaxf(r0 - ppq, r1 + ppq);
      M[2 * 4 + j] = fmaxf(r0 + ppq, r1 - ppq);
      M[1 * 4 + j] = fmaxf(r2 + pmq, r3 - pmq);
      M[3 * 4 + j] = fmaxf(r2 - pmq, r3 + pmq);
    }
  }
}

// one BCJR pass: 4 waves x 64 lanes x SCH steps; branch-free DPP scans
__device__ __forceinline__ void bcjr_pass(
    const float* ys, const float* La, float* dst, const int (&wi)[SCH],
    int finalLLR, const float (&q)[SCH], float (&fT)[4][16],
    int base, int lane, int w) {
  float x[SCH], y[SCH];
  {
    const float4* y4 = (const float4*)(ys + base);
    const float4* l4 = (const float4*)(La + base);
#pragma unroll
    for (int k = 0; k < SCH / 4; ++k) {
      float4 yv = y4[k], lv = l4[k];
      float p0 = yv.x + 0.5f * lv.x, p1 = yv.y + 0.5f * lv.y;
      float p2 = yv.z + 0.5f * lv.z, p3 = yv.w + 0.5f * lv.w;
      x[4 * k + 0] = p0 + q[4 * k + 0]; y[4 * k + 0] = p0 - q[4 * k + 0];
      x[4 * k + 1] = p1 + q[4 * k + 1]; y[4 * k + 1] = p1 - q[4 * k + 1];
      x[4 * k + 2] = p2 + q[4 * k + 2]; y[4 * k + 2] = p2 - q[4 * k + 2];
      x[4 * k + 3] = p3 + q[4 * k + 3]; y[4 * k + 3] = p3 - q[4 * k + 3];
    }
  }

  float P[16];
  buildM(x, y, P);
  float Q[16];
  cp16(Q, P);

  const int row = lane >> 4;

  // ---- fused fwd prefix (full wave) + bwd suffix (in-row) scans ----
  // All levels branch-free: out-of-row shift sources -> old=identity;
  // bcast levels write-masked via row_mask (0xA / 0xC, canonical).
  {
    float Tf[16], Tb[16], Nf[16], Nb[16];
    shift16_id<0x111, 0xF>(P, Tf); shift16_id<0x101, 0xF>(Q, Tb);   // d=1
    comb(P, Tf, Nf); comb(Tb, Q, Nb); cp16(P, Nf); cp16(Q, Nb);
    shift16_id<0x112, 0xF>(P, Tf); shift16_id<0x102, 0xF>(Q, Tb);   // d=2
    comb(P, Tf, Nf); comb(Tb, Q, Nb); cp16(P, Nf); cp16(Q, Nb);
    shift16_id<0x114, 0xF>(P, Tf); shift16_id<0x104, 0xF>(Q, Tb);   // d=4
    comb(P, Tf, Nf); comb(Tb, Q, Nb); cp16(P, Nf); cp16(Q, Nb);
    shift16_id<0x118, 0xF>(P, Tf); shift16_id<0x108, 0xF>(Q, Tb);   // d=8
    comb(P, Tf, Nf); comb(Tb, Q, Nb); cp16(P, Nf); cp16(Q, Nb);
    shift16_id<0x142, 0xA>(P, Tf); comb(P, Tf, Nf); cp16(P, Nf);    // bcast15
    shift16_id<0x143, 0xC>(P, Tf); comb(P, Tf, Nf); cp16(P, Nf);    // bcast31
  }

  // ---- wave total (fwd total == bwd total) -> LDS ----
  if (lane == 63) cp16(fT[w], P);
  __syncthreads();

  // ---- forward vector chain: f = col0 of product of earlier waves' totals ----
  float f[4];
  if (w == 0) { f[0] = 0.f; f[1] = NEGV; f[2] = NEGV; f[3] = NEGV; }
  else {
    f[0] = fT[0][0]; f[1] = fT[0][4]; f[2] = fT[0][8]; f[3] = fT[0][12];
    if (w >= 2) matcol(fT[1], f);
    if (w >= 3) matcol(fT[2], f);
  }
  // ---- backward vector chain: u = colmax over later waves' totals ----
  float u[4];
  if (w == 3) { u[0] = u[1] = u[2] = u[3] = 0.f; }
  else {
    const float* T3 = fT[3];
#pragma unroll
    for (int j = 0; j < 4; ++j)
      u[j] = max4(T3[j], T3[4 + j], T3[8 + j], T3[12 + j]);
    if (w <= 1) rowmat(u, fT[2]);
    if (w == 0) rowmat(u, fT[1]);
  }
  // ---- extend u through later rows' totals within this wave ----
#pragma unroll
  for (int jj = 3; jj >= 1; --jj) {
    float T[16];
#pragma unroll
    for (int e = 0; e < 16; ++e) T[e] = __shfl(Q[e], jj << 4);  // lane jj*16 = row jj total
    if (row < jj) rowmat(u, T);
  }

  // ---- alpha at chunk start: v = P (x) f (inclusive), then shift by one lane ----
  float a[4];
  {
    float v0 = max4(P[0]  + f[0], P[1]  + f[1], P[2]  + f[2], P[3]  + f[3]);
    float v1 = max4(P[4]  + f[0], P[5]  + f[1], P[6]  + f[2], P[7]  + f[3]);
    float v2 = max4(P[8]  + f[0], P[9]  + f[1], P[10] + f[2], P[11] + f[3]);
    float v3 = max4(P[12] + f[0], P[13] + f[1], P[14] + f[2], P[15] + f[3]);
    float a0 = __shfl(v0, lane - 1), a1 = __shfl(v1, lane - 1);
    float a2 = __shfl(v2, lane - 1), a3 = __shfl(v3, lane - 1);
    if (lane == 0) { a0 = f[0]; a1 = f[1]; a2 = f[2]; a3 = f[3]; }
    a[0] = 0.f; a[1] = a1 - a0; a[2] = a2 - a0; a[3] = a3 - a0;
  }

  // ---- beta at chunk end: z = u (x) Q (inclusive suffix colmax), shift by one ----
  float b[4];
  {
    float z0 = max4(u[0] + Q[0], u[1] + Q[4], u[2] + Q[8],  u[3] + Q[12]);
    float z1 = max4(u[0] + Q[1], u[1] + Q[5], u[2] + Q[9],  u[3] + Q[13]);
    float z2 = max4(u[0] + Q[2], u[1] + Q[6], u[2] + Q[10], u[3] + Q[14]);
    float z3 = max4(u[0] + Q[3], u[1] + Q[7], u[2] + Q[11], u[3] + Q[15]);
    float b0 = __shfl(z0, lane + 1), b1 = __shfl(z1, lane + 1);
    float b2 = __shfl(z2, lane + 1), b3 = __shfl(z3, lane + 1);
    if (lane == 63) { b0 = u[0]; b1 = u[1]; b2 = u[2]; b3 = u[3]; }
    b[0] = 0.f; b[1] = b1 - b0; b[2] = b2 - b0; b[3] = b3 - b0;
  }

  // ---- local beta walk ----
  float bet[SCH][4];
  bet[SCH - 1][0] = b[0]; bet[SCH - 1][1] = b[1];
  bet[SCH - 1][2] = b[2]; bet[SCH - 1][3] = b[3];
#pragma unroll
  for (int k = SCH - 1; k >= 1; --k) {
    float ppq = x[k], pmq = y[k];
    float B0 = bet[k][0], B1 = bet[k][1], B2 = bet[k][2], B3 = bet[k][3];
    bet[k - 1][0] = fmaxf(B0 - ppq, B2 + ppq);
    bet[k - 1][1] = fmaxf(B2 - ppq, B0 + ppq);
    bet[k - 1][2] = fmaxf(B3 - pmq, B1 + pmq);
    bet[k - 1][3] = fmaxf(B1 - pmq, B3 + pmq);
  }

  // ---- alpha walk + LLR + scattered write (shared butterfly sums) ----
#pragma unroll
  for (int k = 0; k < SCH; ++k) {
    float ppq = x[k], pmq = y[k];
    float s0m = a[0] - ppq, s1p = a[1] + ppq, s0p = a[0] + ppq, s1m = a[1] - ppq;
    float s2p = a[2] + pmq, s3m = a[3] - pmq, s2m = a[2] - pmq, s3p = a[3] + pmq;
    float B0 = bet[k][0], B1 = bet[k][1], B2 = bet[k][2], B3 = bet[k][3];
    float m1 = max4(s0p + B2, s1p + B0, s2p + B1, s3p + B3);
    float m0 = max4(s0m + B0, s1m + B2, s2m + B3, s3m + B1);
    float llr = m1 - m0;
    // 2*p[k] == x[k] + y[k]
    float val = finalLLR ? llr : (llr - ppq - pmq);
    dst[wi[k]] = val;
    a[0] = fmaxf(s0m, s1p);
    a[2] = fmaxf(s0p, s1m);
    a[1] = fmaxf(s2p, s3m);
    a[3] = fmaxf(s2m, s3p);
  }
}

__device__ __forceinline__ unsigned fsm_compose(unsigned f, unsigned g) {
  unsigned nm = 0;
#pragma unroll
  for (int s = 0; s < 4; ++s) {
    unsigned gs = (g >> (8 * s)) & 3u;
    nm |= ((f >> (8 * gs)) & 0xFFu) << (8 * s);
  }
  return nm;
}

__global__ __launch_bounds__(TPR, 2) void turbo_kernel(
    const int* __restrict__ xg, const float* __restrict__ n1g,
    const float* __restrict__ n2g, const float* __restrict__ n3g,
    const int* __restrict__ pg, float* __restrict__ outg) {
  __shared__ SM sm;
  const int tid = threadIdx.x;
  const int lane = tid & 63, w = tid >> 6;
  const int base = tid * SCH;
  const size_t rb = (size_t)blockIdx.x * KLEN;

  // ---- load inputs ----
  int* Ai = (int*)sm.A;
  for (int i = tid; i < KLEN; i += TPR) {
    sm.perm[i] = (unsigned short)pg[i];
    int xv = xg[rb + i];
    Ai[i] = xv;
    sm.y1[i] = (2.f * xv - 1.f) + n1g[rb + i];
    sm.Lint[i] = 0.f;
  }
  float q2[SCH], q3[SCH];
  {
    size_t g0 = rb + (size_t)base;
#pragma unroll
    for (int k = 0; k < SCH; ++k) { q2[k] = n2g[g0 + k]; q3[k] = n3g[g0 + k]; }
  }
  __syncthreads();

  // ---- one-time: invp, interleaved systematic ----
  for (int i = tid; i < KLEN; i += TPR) {
    sm.invp[sm.perm[i]] = (unsigned short)i;
    sm.y1i[i] = sm.y1[sm.perm[i]];
  }

  // ---- RSC encode via FSM hierarchical scan ----
  unsigned ub1 = 0, ub2 = 0;
#pragma unroll
  for (int k = 0; k < SCH; ++k) {
    int t = base + k;
    ub1 |= (unsigned)(Ai[t] & 1) << k;
    ub2 |= (unsigned)(Ai[sm.perm[t]] & 1) << k;
  }
  unsigned m1 = 0x03020100u, m2 = 0x03020100u;
#pragma unroll
  for (int k = 0; k < SCH; ++k) {
    unsigned st1 = ((ub1 >> k) & 1) ? 0x03010002u : 0x01030200u;
    unsigned st2 = ((ub2 >> k) & 1) ? 0x03010002u : 0x01030200u;
    m1 = fsm_compose(st1, m1);
    m2 = fsm_compose(st2, m2);
  }
#pragma unroll
  for (int i = 0; i < 6; ++i) {
    const int d = 1 << i;
    unsigned t1 = __shfl_up(m1, d), t2 = __shfl_up(m2, d);
    if (lane >= d) { m1 = fsm_compose(m1, t1); m2 = fsm_compose(m2, t2); }
  }
  if (lane == 63) { sm.eT[w][0] = m1; sm.eT[w][1] = m2; }
  __syncthreads();
  {
    unsigned W1 = 0x03020100u, W2 = 0x03020100u;
    if (w >= 1) { W1 = sm.eT[0][0]; W2 = sm.eT[0][1]; }
    if (w >= 2) { W1 = fsm_compose(sm.eT[1][0], W1); W2 = fsm_compose(sm.eT[1][1], W2); }
    if (w >= 3) { W1 = fsm_compose(sm.eT[2][0], W1); W2 = fsm_compose(sm.eT[2][1], W2); }
    unsigned f1 = fsm_compose(m1, W1), f2 = fsm_compose(m2, W2);
    unsigned pf1 = __shfl_up(f1, 1), pf2 = __shfl_up(f2, 1);
    int s1 = (tid == 0) ? 0 : (lane == 0 ? (int)(W1 & 3u) : (int)(pf1 & 3u));
    int s2 = (tid == 0) ? 0 : (lane == 0 ? (int)(W2 & 3u) : (int)(pf2 & 3u));
#pragma unroll
    for (int k = 0; k < SCH; ++k) {
      { int u = (ub1 >> k) & 1, a = u ^ (s1 >> 1) ^ (s1 & 1), par = a ^ (s1 & 1);
        q2[k] += 2.f * par - 1.f; s1 = (a << 1) | (s1 >> 1); }
      { int u = (ub2 >> k) & 1, a = u ^ (s2 >> 1) ^ (s2 & 1), par = a ^ (s2 & 1);
        q3[k] += 2.f * par - 1.f; s2 = (a << 1) | (s2 >> 1); }
    }
  }
  __syncthreads();  // bits consumed; A becomes interleaved-La buffer

  // ---- cache scatter indices in registers (constant across iterations) ----
  int wi1[SCH], wi2[SCH];
#pragma unroll
  for (int k = 0; k < SCH; ++k) {
    wi1[k] = (int)sm.invp[base + k];
    wi2[k] = (int)sm.perm[base + k];
  }

  // ---- 6 turbo iterations ----
#pragma unroll 1
  for (int it = 0; it < 6; ++it) {
    bcjr_pass(sm.y1, sm.Lint, sm.A, wi1, 0, q2, sm.fT, base, lane, w);
    __syncthreads();
    const int fin = (it == 5);
    bcjr_pass(sm.y1i, sm.A, sm.Lint, wi2, fin, q3, sm.fT, base, lane, w);
    __syncthreads();
  }

  // ---- Lint holds deinterleaved L2; coalesced store ----
  for (int i = tid; i < KLEN; i += TPR) outg[rb + i] = sm.Lint[i];
}

extern "C" void kernel_launch(void* const* d_in, const int* in_sizes, int n_in,
                              void* d_out, int out_size, void* d_ws, size_t ws_size,
                              hipStream_t stream) {
  (void)n_in; (void)d_ws; (void)ws_size; (void)out_size;
  const int* x    = (const int*)d_in[0];
  const float* n1 = (const float*)d_in[1];
  const float* n2 = (const float*)d_in[2];
  const float* n3 = (const float*)d_in[3];
  const int* perm = (const int*)d_in[4];
  float* out = (float*)d_out;
  const int K = in_sizes[4];       // 2048
  const int B = in_sizes[0] / K;   // 512 rows, one per block
  turbo_kernel<<<B, TPR, 0, stream>>>(x, n1, n2, n3, perm, out);
}

// Round 12
// 155.334 us; speedup vs baseline: 1.0163x; 1.0163x over previous
//
#include <hip/hip_runtime.h>

#define KLEN 2048
#define SCH 8           // trellis steps per thread
#define TPR 256         // threads per row (4 waves)
#define NEGV (-1e4f)

struct SM {
  float y1[KLEN];             // systematic, natural order
  float y1i[KLEN];            // systematic, interleaved
  float Lint[KLEN];           // La for decoder 1 (natural)
  float A[KLEN];              // La for decoder 2 (interleaved); bits staging
  unsigned short perm[KLEN];
  unsigned short invp[KLEN];
  float fT[4][16];            // per-wave totals (fwd total == bwd total)
  unsigned int eT[4][2];      // encoder wave totals
};

__device__ __forceinline__ float max4(float a, float b, float c, float d) {
  return fmaxf(fmaxf(fmaxf(a, b), c), d);   // v_max3 + v_max
}

// DPP shift with old = inline 0, bound_ctrl=1: single non-RMW v_mov_dpp.
// Invalid lanes get 0 but are exec-predicated off in every consumer.
// (R11 post-mortem: identity-valued `old` forces a mov + RMW dependency per
// element — measurably worse than these exec guards.)
template <int CTRL>
__device__ __forceinline__ float dppf(float src) {
  return __int_as_float(__builtin_amdgcn_update_dpp(
      0, __float_as_int(src), CTRL, 0xF, 0xF, true));
}

template <int CTRL>
__device__ __forceinline__ void shift16(const float (&X)[16], float (&T)[16]) {
#pragma unroll
  for (int e = 0; e < 16; ++e) T[e] = dppf<CTRL>(X[e]);
}

__device__ __forceinline__ void cp16(float (&D)[16], const float (&S)[16]) {
#pragma unroll
  for (int e = 0; e < 16; ++e) D[e] = S[e];
}

// Z = X (later) (x) Y (earlier), max-plus, row-major M[i*4+k]
__device__ __forceinline__ void comb(const float (&X)[16], const float (&Y)[16],
                                     float (&Z)[16]) {
#pragma unroll
  for (int i = 0; i < 4; ++i)
#pragma unroll
    for (int j = 0; j < 4; ++j)
      Z[i * 4 + j] = max4(X[i * 4 + 0] + Y[0 * 4 + j], X[i * 4 + 1] + Y[1 * 4 + j],
                          X[i * 4 + 2] + Y[2 * 4 + j], X[i * 4 + 3] + Y[3 * 4 + j]);
}

// f' = T (x) f  (column-vector pushed forward through later matrix T)
__device__ __forceinline__ void matcol(const float* T, float (&f)[4]) {
  float r0 = max4(T[0]  + f[0], T[1]  + f[1], T[2]  + f[2], T[3]  + f[3]);
  float r1 = max4(T[4]  + f[0], T[5]  + f[1], T[6]  + f[2], T[7]  + f[3]);
  float r2 = max4(T[8]  + f[0], T[9]  + f[1], T[10] + f[2], T[11] + f[3]);
  float r3 = max4(T[12] + f[0], T[13] + f[1], T[14] + f[2], T[15] + f[3]);
  f[0] = r0; f[1] = r1; f[2] = r2; f[3] = r3;
}

// u' = u (x) T  (row-vector pulled backward through earlier matrix T)
__device__ __forceinline__ void rowmat(float (&u)[4], const float* T) {
  float c0 = max4(u[0] + T[0], u[1] + T[4], u[2] + T[8],  u[3] + T[12]);
  float c1 = max4(u[0] + T[1], u[1] + T[5], u[2] + T[9],  u[3] + T[13]);
  float c2 = max4(u[0] + T[2], u[1] + T[6], u[2] + T[10], u[3] + T[14]);
  float c3 = max4(u[0] + T[3], u[1] + T[7], u[2] + T[11], u[3] + T[15]);
  u[0] = c0; u[1] = c1; u[2] = c2; u[3] = c3;
}

// chunk matrix over SCH steps from butterfly terms x=p+q, y=p-q.
// Steps 0+1 fused (pure adds). NO normalization.
__device__ __forceinline__ void buildM(const float (&x)[SCH], const float (&y)[SCH],
                                       float (&M)[16]) {
  const float x0 = x[0], y0 = y[0], x1 = x[1], y1 = y[1];
  M[0]  = -x0 - x1;  M[4]  =  x0 + y1;  M[8]  = -x0 + x1;  M[12] =  x0 - y1;  // col0
  M[1]  =  x0 - x1;  M[5]  = -x0 + y1;  M[9]  =  x0 + x1;  M[13] = -x0 - y1;  // col1
  M[2]  =  y0 + x1;  M[6]  = -y0 - y1;  M[10] =  y0 - x1;  M[14] = -y0 + y1;  // col2
  M[3]  = -y0 + x1;  M[7]  =  y0 - y1;  M[11] = -y0 - x1;  M[15] =  y0 + y1;  // col3
#pragma unroll
  for (int k = 2; k < SCH; ++k) {
    float ppq = x[k], pmq = y[k];
#pragma unroll
    for (int j = 0; j < 4; ++j) {
      float r0 = M[0 * 4 + j], r1 = M[1 * 4 + j], r2 = M[2 * 4 + j], r3 = M[3 * 4 + j];
      M[0 * 4 + j] = fmaxf(r0 - ppq, r1 + ppq);
      M[2 * 4 + j] = fmaxf(r0 + ppq, r1 - ppq);
      M[1 * 4 + j] = fmaxf(r2 + pmq, r3 - pmq);
      M[3 * 4 + j] = fmaxf(r2 - pmq, r3 + pmq);
    }
  }
}

// one BCJR pass: 4 waves x 64 lanes x SCH steps; matrix scan + vector tails
__device__ __forceinline__ void bcjr_pass(
    const float* ys, const float* La, float* dst, const int (&wi)[SCH],
    int finalLLR, const float (&q)[SCH], float (&fT)[4][16],
    int base, int lane, int w) {
  float x[SCH], y[SCH];
  {
    const float4* y4 = (const float4*)(ys + base);
    const float4* l4 = (const float4*)(La + base);
#pragma unroll
    for (int k = 0; k < SCH / 4; ++k) {
      float4 yv = y4[k], lv = l4[k];
      float p0 = yv.x + 0.5f * lv.x, p1 = yv.y + 0.5f * lv.y;
      float p2 = yv.z + 0.5f * lv.z, p3 = yv.w + 0.5f * lv.w;
      x[4 * k + 0] = p0 + q[4 * k + 0]; y[4 * k + 0] = p0 - q[4 * k + 0];
      x[4 * k + 1] = p1 + q[4 * k + 1]; y[4 * k + 1] = p1 - q[4 * k + 1];
      x[4 * k + 2] = p2 + q[4 * k + 2]; y[4 * k + 2] = p2 - q[4 * k + 2];
      x[4 * k + 3] = p3 + q[4 * k + 3]; y[4 * k + 3] = p3 - q[4 * k + 3];
    }
  }

  float P[16];
  buildM(x, y, P);
  float Q[16];
  cp16(Q, P);

  const int rl = lane & 15;
  const int row = lane >> 4;

  // ---- fwd inclusive prefix scan, full 64 lanes (6 DPP levels) ----
  {
    float T[16], N[16];
    shift16<0x111>(P, T); if (rl >= 1) { comb(P, T, N); cp16(P, N); }
    shift16<0x112>(P, T); if (rl >= 2) { comb(P, T, N); cp16(P, N); }
    shift16<0x114>(P, T); if (rl >= 4) { comb(P, T, N); cp16(P, N); }
    shift16<0x118>(P, T); if (rl >= 8) { comb(P, T, N); cp16(P, N); }
    shift16<0x142>(P, T); if (row & 1)  { comb(P, T, N); cp16(P, N); }  // bcast15
    shift16<0x143>(P, T); if (row >= 2) { comb(P, T, N); cp16(P, N); }  // bcast31
  }
  // ---- bwd inclusive suffix scan, IN-ROW ONLY (4 DPP levels) ----
  {
    float T[16], N[16];
    shift16<0x101>(Q, T); if (rl <= 14) { comb(T, Q, N); cp16(Q, N); }
    shift16<0x102>(Q, T); if (rl <= 13) { comb(T, Q, N); cp16(Q, N); }
    shift16<0x104>(Q, T); if (rl <= 11) { comb(T, Q, N); cp16(Q, N); }
    shift16<0x108>(Q, T); if (rl <= 7)  { comb(T, Q, N); cp16(Q, N); }
  }

  // ---- wave total (fwd total == bwd total) -> LDS ----
  if (lane == 63) cp16(fT[w], P);
  __syncthreads();

  // ---- forward vector chain: f = col0 of product of earlier waves' totals ----
  float f[4];
  if (w == 0) { f[0] = 0.f; f[1] = NEGV; f[2] = NEGV; f[3] = NEGV; }
  else {
    f[0] = fT[0][0]; f[1] = fT[0][4]; f[2] = fT[0][8]; f[3] = fT[0][12];
    if (w >= 2) matcol(fT[1], f);
    if (w >= 3) matcol(fT[2], f);
  }
  // ---- backward vector chain: u = colmax over later waves' totals ----
  float u[4];
  if (w == 3) { u[0] = u[1] = u[2] = u[3] = 0.f; }
  else {
    const float* T3 = fT[3];
#pragma unroll
    for (int j = 0; j < 4; ++j)
      u[j] = max4(T3[j], T3[4 + j], T3[8 + j], T3[12 + j]);
    if (w <= 1) rowmat(u, fT[2]);
    if (w == 0) rowmat(u, fT[1]);
  }
  // ---- extend u through later rows' totals within this wave ----
#pragma unroll
  for (int jj = 3; jj >= 1; --jj) {
    float T[16];
#pragma unroll
    for (int e = 0; e < 16; ++e) T[e] = __shfl(Q[e], jj << 4);  // lane jj*16 = row jj total
    if (row < jj) rowmat(u, T);
  }

  // ---- alpha at chunk start: v = P (x) f (inclusive), then shift by one lane ----
  float a[4];
  {
    float v0 = max4(P[0]  + f[0], P[1]  + f[1], P[2]  + f[2], P[3]  + f[3]);
    float v1 = max4(P[4]  + f[0], P[5]  + f[1], P[6]  + f[2], P[7]  + f[3]);
    float v2 = max4(P[8]  + f[0], P[9]  + f[1], P[10] + f[2], P[11] + f[3]);
    float v3 = max4(P[12] + f[0], P[13] + f[1], P[14] + f[2], P[15] + f[3]);
    float a0 = __shfl(v0, lane - 1), a1 = __shfl(v1, lane - 1);
    float a2 = __shfl(v2, lane - 1), a3 = __shfl(v3, lane - 1);
    if (lane == 0) { a0 = f[0]; a1 = f[1]; a2 = f[2]; a3 = f[3]; }
    a[0] = 0.f; a[1] = a1 - a0; a[2] = a2 - a0; a[3] = a3 - a0;
  }

  // ---- beta at chunk end: z = u (x) Q (inclusive suffix colmax), shift by one ----
  float b[4];
  {
    float z0 = max4(u[0] + Q[0], u[1] + Q[4], u[2] + Q[8],  u[3] + Q[12]);
    float z1 = max4(u[0] + Q[1], u[1] + Q[5], u[2] + Q[9],  u[3] + Q[13]);
    float z2 = max4(u[0] + Q[2], u[1] + Q[6], u[2] + Q[10], u[3] + Q[14]);
    float z3 = max4(u[0] + Q[3], u[1] + Q[7], u[2] + Q[11], u[3] + Q[15]);
    float b0 = __shfl(z0, lane + 1), b1 = __shfl(z1, lane + 1);
    float b2 = __shfl(z2, lane + 1), b3 = __shfl(z3, lane + 1);
    if (lane == 63) { b0 = u[0]; b1 = u[1]; b2 = u[2]; b3 = u[3]; }
    b[0] = 0.f; b[1] = b1 - b0; b[2] = b2 - b0; b[3] = b3 - b0;
  }

  // ---- local beta walk ----
  float bet[SCH][4];
  bet[SCH - 1][0] = b[0]; bet[SCH - 1][1] = b[1];
  bet[SCH - 1][2] = b[2]; bet[SCH - 1][3] = b[3];
#pragma unroll
  for (int k = SCH - 1; k >= 1; --k) {
    float ppq = x[k], pmq = y[k];
    float B0 = bet[k][0], B1 = bet[k][1], B2 = bet[k][2], B3 = bet[k][3];
    bet[k - 1][0] = fmaxf(B0 - ppq, B2 + ppq);
    bet[k - 1][1] = fmaxf(B2 - ppq, B0 + ppq);
    bet[k - 1][2] = fmaxf(B3 - pmq, B1 + pmq);
    bet[k - 1][3] = fmaxf(B1 - pmq, B3 + pmq);
  }

  // ---- alpha walk + LLR + scattered write (shared butterfly sums) ----
#pragma unroll
  for (int k = 0; k < SCH; ++k) {
    float ppq = x[k], pmq = y[k];
    float s0m = a[0] - ppq, s1p = a[1] + ppq, s0p = a[0] + ppq, s1m = a[1] - ppq;
    float s2p = a[2] + pmq, s3m = a[3] - pmq, s2m = a[2] - pmq, s3p = a[3] + pmq;
    float B0 = bet[k][0], B1 = bet[k][1], B2 = bet[k][2], B3 = bet[k][3];
    float m1 = max4(s0p + B2, s1p + B0, s2p + B1, s3p + B3);
    float m0 = max4(s0m + B0, s1m + B2, s2m + B3, s3m + B1);
    float llr = m1 - m0;
    // 2*p[k] == x[k] + y[k]
    float val = finalLLR ? llr : (llr - ppq - pmq);
    dst[wi[k]] = val;
    a[0] = fmaxf(s0m, s1p);
    a[2] = fmaxf(s0p, s1m);
    a[1] = fmaxf(s2p, s3m);
    a[3] = fmaxf(s2m, s3p);
  }
}

__device__ __forceinline__ unsigned fsm_compose(unsigned f, unsigned g) {
  unsigned nm = 0;
#pragma unroll
  for (int s = 0; s < 4; ++s) {
    unsigned gs = (g >> (8 * s)) & 3u;
    nm |= ((f >> (8 * gs)) & 0xFFu) << (8 * s);
  }
  return nm;
}

__global__ __launch_bounds__(TPR, 2) void turbo_kernel(
    const int* __restrict__ xg, const float* __restrict__ n1g,
    const float* __restrict__ n2g, const float* __restrict__ n3g,
    const int* __restrict__ pg, float* __restrict__ outg) {
  __shared__ SM sm;
  const int tid = threadIdx.x;
  const int lane = tid & 63, w = tid >> 6;
  const int base = tid * SCH;
  const size_t rb = (size_t)blockIdx.x * KLEN;

  // ---- load inputs ----
  int* Ai = (int*)sm.A;
  for (int i = tid; i < KLEN; i += TPR) {
    sm.perm[i] = (unsigned short)pg[i];
    int xv = xg[rb + i];
    Ai[i] = xv;
    sm.y1[i] = (2.f * xv - 1.f) + n1g[rb + i];
    sm.Lint[i] = 0.f;
  }
  float q2[SCH], q3[SCH];
  {
    size_t g0 = rb + (size_t)base;
#pragma unroll
    for (int k = 0; k < SCH; ++k) { q2[k] = n2g[g0 + k]; q3[k] = n3g[g0 + k]; }
  }
  __syncthreads();

  // ---- one-time: invp, interleaved systematic ----
  for (int i = tid; i < KLEN; i += TPR) {
    sm.invp[sm.perm[i]] = (unsigned short)i;
    sm.y1i[i] = sm.y1[sm.perm[i]];
  }

  // ---- RSC encode via FSM hierarchical scan ----
  unsigned ub1 = 0, ub2 = 0;
#pragma unroll
  for (int k = 0; k < SCH; ++k) {
    int t = base + k;
    ub1 |= (unsigned)(Ai[t] & 1) << k;
    ub2 |= (unsigned)(Ai[sm.perm[t]] & 1) << k;
  }
  unsigned m1 = 0x03020100u, m2 = 0x03020100u;
#pragma unroll
  for (int k = 0; k < SCH; ++k) {
    unsigned st1 = ((ub1 >> k) & 1) ? 0x03010002u : 0x01030200u;
    unsigned st2 = ((ub2 >> k) & 1) ? 0x03010002u : 0x01030200u;
    m1 = fsm_compose(st1, m1);
    m2 = fsm_compose(st2, m2);
  }
#pragma unroll
  for (int i = 0; i < 6; ++i) {
    const int d = 1 << i;
    unsigned t1 = __shfl_up(m1, d), t2 = __shfl_up(m2, d);
    if (lane >= d) { m1 = fsm_compose(m1, t1); m2 = fsm_compose(m2, t2); }
  }
  if (lane == 63) { sm.eT[w][0] = m1; sm.eT[w][1] = m2; }
  __syncthreads();
  {
    unsigned W1 = 0x03020100u, W2 = 0x03020100u;
    if (w >= 1) { W1 = sm.eT[0][0]; W2 = sm.eT[0][1]; }
    if (w >= 2) { W1 = fsm_compose(sm.eT[1][0], W1); W2 = fsm_compose(sm.eT[1][1], W2); }
    if (w >= 3) { W1 = fsm_compose(sm.eT[2][0], W1); W2 = fsm_compose(sm.eT[2][1], W2); }
    unsigned f1 = fsm_compose(m1, W1), f2 = fsm_compose(m2, W2);
    unsigned pf1 = __shfl_up(f1, 1), pf2 = __shfl_up(f2, 1);
    int s1 = (tid == 0) ? 0 : (lane == 0 ? (int)(W1 & 3u) : (int)(pf1 & 3u));
    int s2 = (tid == 0) ? 0 : (lane == 0 ? (int)(W2 & 3u) : (int)(pf2 & 3u));
#pragma unroll
    for (int k = 0; k < SCH; ++k) {
      { int u = (ub1 >> k) & 1, a = u ^ (s1 >> 1) ^ (s1 & 1), par = a ^ (s1 & 1);
        q2[k] += 2.f * par - 1.f; s1 = (a << 1) | (s1 >> 1); }
      { int u = (ub2 >> k) & 1, a = u ^ (s2 >> 1) ^ (s2 & 1), par = a ^ (s2 & 1);
        q3[k] += 2.f * par - 1.f; s2 = (a << 1) | (s2 >> 1); }
    }
  }
  __syncthreads();  // bits consumed; A becomes interleaved-La buffer

  // ---- cache scatter indices in registers (constant across iterations) ----
  int wi1[SCH], wi2[SCH];
#pragma unroll
  for (int k = 0; k < SCH; ++k) {
    wi1[k] = (int)sm.invp[base + k];
    wi2[k] = (int)sm.perm[base + k];
  }

  // ---- 6 turbo iterations ----
#pragma unroll 1
  for (int it = 0; it < 6; ++it) {
    bcjr_pass(sm.y1, sm.Lint, sm.A, wi1, 0, q2, sm.fT, base, lane, w);
    __syncthreads();
    const int fin = (it == 5);
    bcjr_pass(sm.y1i, sm.A, sm.Lint, wi2, fin, q3, sm.fT, base, lane, w);
    __syncthreads();
  }

  // ---- Lint holds deinterleaved L2; coalesced store ----
  for (int i = tid; i < KLEN; i += TPR) outg[rb + i] = sm.Lint[i];
}

extern "C" void kernel_launch(void* const* d_in, const int* in_sizes, int n_in,
                              void* d_out, int out_size, void* d_ws, size_t ws_size,
                              hipStream_t stream) {
  (void)n_in; (void)d_ws; (void)ws_size; (void)out_size;
  const int* x    = (const int*)d_in[0];
  const float* n1 = (const float*)d_in[1];
  const float* n2 = (const float*)d_in[2];
  const float* n3 = (const float*)d_in[3];
  const int* perm = (const int*)d_in[4];
  float* out = (float*)d_out;
  const int K = in_sizes[4];       // 2048
  const int B = in_sizes[0] / K;   // 512 rows, one per block
  turbo_kernel<<<B, TPR, 0, stream>>>(x, n1, n2, n3, perm, out);
}